// Round 3
// baseline (399.329 us; speedup 1.0000x reference)
//
#include <hip/hip_runtime.h>
#include <stdint.h>

typedef __attribute__((ext_vector_type(4)))  int i32x4;
typedef __attribute__((ext_vector_type(16))) int i32x16;

#define M_TOK 8192
#define N_OUT 4096
#define K_IN  4096

// gemm geometry: 256x256 tile, BK = 64 i8 (64 B/row), 8 waves (2Mx4N),
// per-wave 128x64 output = 4x2 of mfma_i32_32x32x32_i8.
#define BM 256
#define BN 256
#define BKB 64            // bytes of K per tile
#define NT (K_IN / BKB)   // 64 K-tiles
#define SLOT_BYTES 32768  // A 16KB + B 16KB per slot
#define B_OFF 16384

// global->LDS direct copy, 16B per lane. LDS dest MUST be the wave-uniform
// base: HW writes lane L's 16B at (base + L*16).
#define GLDS16(gp, lp)                                                         \
  __builtin_amdgcn_global_load_lds(                                            \
      (const __attribute__((address_space(1))) void*)(gp),                     \
      (__attribute__((address_space(3))) void*)(lp), 16, 0, 0)

#define VM4 asm volatile("s_waitcnt vmcnt(4)" ::: "memory")
#define VM0 asm volatile("s_waitcnt vmcnt(0)" ::: "memory")
#define NOPX ((void)0)

// ---------------------------------------------------------------------------
// Fused quantization: blocks [0, M_TOK) do per-row i8 quant of x;
// blocks [M_TOK, M_TOK+4096) do sign(w) -> i8. One launch instead of two.
// ---------------------------------------------------------------------------
__global__ void __launch_bounds__(256) quant_fused(
    const float* __restrict__ x, const float* __restrict__ w,
    char* __restrict__ xq, char* __restrict__ wq, float* __restrict__ scales) {
  __shared__ float wmax[4];
  const int t = threadIdx.x;

  if (blockIdx.x < M_TOK) {
    const int row = blockIdx.x;
    const float4* rp = (const float4*)(x + (size_t)row * K_IN);

    float4 v[4];
#pragma unroll
    for (int p = 0; p < 4; p++) v[p] = rp[p * 256 + t];

    float amax = 0.f;
#pragma unroll
    for (int p = 0; p < 4; p++)
      amax = fmaxf(amax, fmaxf(fmaxf(fabsf(v[p].x), fabsf(v[p].y)),
                               fmaxf(fabsf(v[p].z), fabsf(v[p].w))));

#pragma unroll
    for (int off = 32; off > 0; off >>= 1)
      amax = fmaxf(amax, __shfl_xor(amax, off));

    if ((t & 63) == 0) wmax[t >> 6] = amax;
    __syncthreads();
    amax = fmaxf(fmaxf(wmax[0], wmax[1]), fmaxf(wmax[2], wmax[3]));
    amax = fmaxf(amax, 1e-30f);

    const float inv = 127.f / amax;
    if (t == 0) scales[row] = amax / 127.f;

    uint32_t* op = (uint32_t*)(xq + (size_t)row * K_IN);
#pragma unroll
    for (int p = 0; p < 4; p++) {
      uint32_t b0 = (uint32_t)(__float2int_rn(v[p].x * inv) & 0xFF);
      uint32_t b1 = (uint32_t)(__float2int_rn(v[p].y * inv) & 0xFF);
      uint32_t b2 = (uint32_t)(__float2int_rn(v[p].z * inv) & 0xFF);
      uint32_t b3 = (uint32_t)(__float2int_rn(v[p].w * inv) & 0xFF);
      op[p * 256 + t] = b0 | (b1 << 8) | (b2 << 16) | (b3 << 24);
    }
  } else {
    const size_t base = (size_t)(blockIdx.x - M_TOK) * 1024;  // float4 units
    const float4* p = (const float4*)w + base;
    uint32_t* op = (uint32_t*)wq + base;
#pragma unroll
    for (int q = 0; q < 4; q++) {
      float4 f = p[q * 256 + t];
      int s0 = (f.x > 0.f) - (f.x < 0.f);
      int s1 = (f.y > 0.f) - (f.y < 0.f);
      int s2 = (f.z > 0.f) - (f.z < 0.f);
      int s3 = (f.w > 0.f) - (f.w < 0.f);
      op[q * 256 + t] = (uint32_t)(s0 & 0xFF) | ((uint32_t)(s1 & 0xFF) << 8) |
                        ((uint32_t)(s2 & 0xFF) << 16) | ((uint32_t)(s3 & 0xFF) << 24);
    }
  }
}

// ---------------------------------------------------------------------------
// C[m][n] = scale[m] * (sum_k Aq[m][k] * Wq[n][k]) + bias[n]
//
// m201-style phased schedule (T3+T4+T5). Iteration = 2 K-tiles, 4 phases.
// Each phase: {6x ds_read_b128 frags | 2x global_load_lds (A- or B-half of a
// tile 2..3 ahead) | counted vmcnt at P2/P4} -> barrier -> setprio(1) ->
// 8x MFMA -> setprio(0) -> barrier.
//
// vmcnt derivation (2 GLDS/phase/wave, 8/iter): at P2 outstanding = 8
// {A(t+1),B(t+1),A(t+2),B(t+2)}; vmcnt(4) drains tile t+1 -> ready for P3/P4.
// At P4 outstanding = {A(t+2),B(t+2),A(t+3),B(t+3)}; vmcnt(4) drains tile
// t+2 -> ready for next iter's P1/P2. Never 0 until the 2-tile tail.
//
// Slot ring: tile tau -> slot tau&3 (128 KB). WAR: the GLDS at P1(I) targets
// the slot of tile 2I-2, whose last ds_reads were lgkm-complete before
// P2(I-1)'s trailing barrier -- two barriers upstream. Safe.
//
// LDS swizzle (unchanged): row r stores 16B chunk c at slot c ^ ((r>>1)&3);
// global source pre-swizzled (lane L: chunk (L&3)^((L>>3)&3)); fragment reads
// then spread every 8 rows over all 32 banks.
// ---------------------------------------------------------------------------
__global__ void __launch_bounds__(512, 2) gemm_bin_i8(
    const char* __restrict__ A, const char* __restrict__ B,
    const float* __restrict__ scales, const float* __restrict__ bias,
    float* __restrict__ C) {
  __shared__ __align__(16) char lds[4 * SLOT_BYTES];  // 128 KB

  const int tid  = threadIdx.x;
  const int lane = tid & 63;
  const int wv   = tid >> 6;   // 0..7
  const int wm   = wv >> 2;    // 0..1  (M half)
  const int wn   = wv & 3;     // 0..3  (N quarter)

  // XCD-aware bijective swizzle: 512 blocks, 8 XCDs, 64 per XCD chunk.
  int bid = (int)blockIdx.x;
  bid = (bid & 7) * (512 >> 3) + (bid >> 3);
  const int m0 = (bid >> 4) * BM;  // 32 m-tiles
  const int n0 = (bid & 15) * BN;  // 16 n-tiles

  // ---- staging: wave wv owns rows [wv*32, wv*32+32); per half-tile 2 GLDS16
  // (16 rows / 1024 B each).
  const int srow   = lane >> 2;                       // 0..15
  const int schunk = (lane & 3) ^ ((lane >> 3) & 3);  // pre-swizzled source chunk
  const char* gAb = A + (size_t)(m0 + wv * 32 + srow) * K_IN + schunk * 16;
  const char* gBb = B + (size_t)(n0 + wv * 32 + srow) * K_IN + schunk * 16;
  // WAVE-UNIFORM LDS bases (HW adds lane*16 itself).
  char* lAb = lds + wv * 2048;
  char* lBb = lds + B_OFF + wv * 2048;

  auto stageA = [&](int tt) {
    const size_t ko = (size_t)tt * BKB;
    char* l = lAb + (tt & 3) * SLOT_BYTES;
    GLDS16(gAb + ko, l);
    GLDS16(gAb + ko + (size_t)16 * K_IN, l + 1024);
  };
  auto stageB = [&](int tt) {
    const size_t ko = (size_t)tt * BKB;
    char* l = lBb + (tt & 3) * SLOT_BYTES;
    GLDS16(gBb + ko, l);
    GLDS16(gBb + ko + (size_t)16 * K_IN, l + 1024);
  };

  // ---- fragment read constants
  const int fr  = lane & 31;         // row within 32-row subtile
  const int k16 = lane >> 5;         // which 16B half of the 32-i8 k-slice
  const int x3  = (lane >> 1) & 3;   // swizzle term ((row>>1)&3)
  const int aoff = wm * 8192 + fr * 64;           // wm*128 rows
  const int boff = B_OFF + wn * 4096 + fr * 64;   // wn*64 rows

  i32x16 acc[4][2];
#pragma unroll
  for (int m = 0; m < 4; m++)
#pragma unroll
    for (int n = 0; n < 2; n++)
#pragma unroll
      for (int r = 0; r < 16; r++) acc[m][n][r] = 0;

#define PHASE(rtile, ks, STAGE_STMT, VM_STMT)                                  \
  {                                                                            \
    const char* pA = lds + ((rtile) & 3) * SLOT_BYTES + aoff;                  \
    const char* pB = lds + ((rtile) & 3) * SLOT_BYTES + boff;                  \
    const int so = ((2 * (ks) + k16) ^ x3) << 4;                               \
    i32x4 a0 = *(const i32x4*)(pA + so);                                       \
    i32x4 a1 = *(const i32x4*)(pA + 2048 + so);                                \
    i32x4 a2 = *(const i32x4*)(pA + 4096 + so);                                \
    i32x4 a3 = *(const i32x4*)(pA + 6144 + so);                                \
    i32x4 b0 = *(const i32x4*)(pB + so);                                       \
    i32x4 b1 = *(const i32x4*)(pB + 2048 + so);                                \
    STAGE_STMT;                                                                \
    VM_STMT;                                                                   \
    __builtin_amdgcn_sched_barrier(0);                                         \
    __builtin_amdgcn_s_barrier();                                              \
    __builtin_amdgcn_sched_barrier(0);                                         \
    __builtin_amdgcn_s_setprio(1);                                             \
    acc[0][0] = __builtin_amdgcn_mfma_i32_32x32x32_i8(a0, b0, acc[0][0], 0, 0, 0); \
    acc[0][1] = __builtin_amdgcn_mfma_i32_32x32x32_i8(a0, b1, acc[0][1], 0, 0, 0); \
    acc[1][0] = __builtin_amdgcn_mfma_i32_32x32x32_i8(a1, b0, acc[1][0], 0, 0, 0); \
    acc[1][1] = __builtin_amdgcn_mfma_i32_32x32x32_i8(a1, b1, acc[1][1], 0, 0, 0); \
    acc[2][0] = __builtin_amdgcn_mfma_i32_32x32x32_i8(a2, b0, acc[2][0], 0, 0, 0); \
    acc[2][1] = __builtin_amdgcn_mfma_i32_32x32x32_i8(a2, b1, acc[2][1], 0, 0, 0); \
    acc[3][0] = __builtin_amdgcn_mfma_i32_32x32x32_i8(a3, b0, acc[3][0], 0, 0, 0); \
    acc[3][1] = __builtin_amdgcn_mfma_i32_32x32x32_i8(a3, b1, acc[3][1], 0, 0, 0); \
    __builtin_amdgcn_s_setprio(0);                                             \
    __builtin_amdgcn_sched_barrier(0);                                         \
    __builtin_amdgcn_s_barrier();                                              \
  }

  // ---- prologue: stage tiles 0,1 (8 GLDS/wave in flight); tile 0 ready.
  stageA(0); stageB(0); stageA(1); stageB(1);
  VM4;
  __builtin_amdgcn_sched_barrier(0);
  __builtin_amdgcn_s_barrier();
  __builtin_amdgcn_sched_barrier(0);

  // ---- main loop: I = 0..30 computes tiles {2I, 2I+1}, stages {2I+2, 2I+3}
  for (int I = 0; I < 31; ++I) {
    const int t0 = 2 * I, t1 = t0 + 1, u0 = t0 + 2, u1 = t0 + 3;
    PHASE(t0, 0, stageA(u0), NOPX);
    PHASE(t0, 1, stageB(u0), VM4);
    PHASE(t1, 0, stageA(u1), NOPX);
    PHASE(t1, 1, stageB(u1), VM4);
  }
  // ---- tail: tiles 62, 63 (already staged; drain vmcnt to 0 before 63)
  PHASE(62, 0, NOPX, NOPX);
  PHASE(62, 1, NOPX, VM0);
  PHASE(63, 0, NOPX, NOPX);
  PHASE(63, 1, NOPX, NOPX);
#undef PHASE

  // ---- epilogue: 32x32 C/D layout col=lane&31, row=(r&3)+8*(r>>2)+4*(lane>>5)
  const int col0 = n0 + wn * 64 + (lane & 31);
  const float bv0 = bias[col0];
  const float bv1 = bias[col0 + 32];
#pragma unroll
  for (int m = 0; m < 4; m++) {
    const int rb = m0 + wm * 128 + m * 32 + ((lane >> 5) << 2);
#pragma unroll
    for (int r = 0; r < 16; r++) {
      const int row = rb + (r & 3) + ((r >> 2) << 3);
      const float sc = scales[row];
      float* cp = C + (size_t)row * N_OUT + col0;
      cp[0]  = (float)acc[m][0][r] * sc + bv0;
      cp[32] = (float)acc[m][1][r] * sc + bv1;
    }
  }
}

// emergency fallback if ws too small (correct but slow)
__global__ void fallback_gemm(const float* __restrict__ x, const float* __restrict__ w,
                              const float* __restrict__ bias, float* __restrict__ out) {
  int idx = blockIdx.x * blockDim.x + threadIdx.x;
  if (idx >= M_TOK * N_OUT) return;
  int row = idx / N_OUT, col = idx % N_OUT;
  const float* xp = x + (size_t)row * K_IN;
  const float* wp = w + (size_t)col * K_IN;
  float s = 0.f;
  for (int k = 0; k < K_IN; k++) {
    float wv = wp[k];
    float sg = wv > 0.f ? 1.f : (wv < 0.f ? -1.f : 0.f);
    s += xp[k] * sg;
  }
  out[idx] = s + bias[col];
}

extern "C" void kernel_launch(void* const* d_in, const int* in_sizes, int n_in,
                              void* d_out, int out_size, void* d_ws, size_t ws_size,
                              hipStream_t stream) {
  const float* x    = (const float*)d_in[0];
  const float* w    = (const float*)d_in[1];
  const float* bias = (const float*)d_in[2];
  float* out = (float*)d_out;

  const size_t xq_bytes = (size_t)M_TOK * K_IN;           // 32 MiB
  const size_t wq_bytes = (size_t)N_OUT * K_IN;           // 16 MiB
  const size_t sc_bytes = (size_t)M_TOK * sizeof(float);  // 32 KiB

  if (ws_size < xq_bytes + wq_bytes + sc_bytes) {
    int total = M_TOK * N_OUT;
    fallback_gemm<<<(total + 255) / 256, 256, 0, stream>>>(x, w, bias, out);
    return;
  }

  char*  xq = (char*)d_ws;
  char*  wq = (char*)d_ws + xq_bytes;
  float* sc = (float*)((char*)d_ws + xq_bytes + wq_bytes);

  // one fused quant launch: 8192 x-row blocks + 4096 w-sign blocks
  quant_fused<<<M_TOK + (N_OUT * K_IN / 4) / 1024, 256, 0, stream>>>(x, w, xq, wq, sc);

  // 32 x 16 = 512 blocks of 512 threads (8 waves), 128 KB LDS -> 1 block/CU
  gemm_bin_i8<<<512, 512, 0, stream>>>(xq, wq, sc, bias, out);
}

// Round 4
// 397.319 us; speedup vs baseline: 1.0051x; 1.0051x over previous
//
#include <hip/hip_runtime.h>
#include <stdint.h>

typedef __attribute__((ext_vector_type(4)))  int i32x4;
typedef __attribute__((ext_vector_type(16))) int i32x16;

#define M_TOK 8192
#define N_OUT 4096
#define K_IN  4096

// gemm geometry: 256x256 tile, BK = 64 i8 (64 B/row), 8 waves (2Mx4N),
// per-wave 128x64 output = 4x2 of mfma_i32_32x32x32_i8.
#define BM 256
#define BN 256
#define BKB 64            // bytes of K per tile
#define NT (K_IN / BKB)   // 64 K-tiles
#define SLOT_BYTES 32768  // A 16KB + B 16KB per slot
#define B_OFF 16384

// global->LDS direct copy, 16B per lane. LDS dest MUST be the wave-uniform
// base: HW writes lane L's 16B at (base + L*16).
#define GLDS16(gp, lp)                                                         \
  __builtin_amdgcn_global_load_lds(                                            \
      (const __attribute__((address_space(1))) void*)(gp),                     \
      (__attribute__((address_space(3))) void*)(lp), 16, 0, 0)

#define VM4 asm volatile("s_waitcnt vmcnt(4)" ::: "memory")
#define VM8 asm volatile("s_waitcnt vmcnt(8)" ::: "memory")
#define VM0 asm volatile("s_waitcnt vmcnt(0)" ::: "memory")
#define SB0 __builtin_amdgcn_sched_barrier(0)
#define NOPX ((void)0)

// ---------------------------------------------------------------------------
// Fused quantization: blocks [0, M_TOK) do per-row i8 quant of x;
// blocks [M_TOK, M_TOK+4096) do sign(w) -> i8.
// ---------------------------------------------------------------------------
__global__ void __launch_bounds__(256) quant_fused(
    const float* __restrict__ x, const float* __restrict__ w,
    char* __restrict__ xq, char* __restrict__ wq, float* __restrict__ scales) {
  __shared__ float wmax[4];
  const int t = threadIdx.x;

  if (blockIdx.x < M_TOK) {
    const int row = blockIdx.x;
    const float4* rp = (const float4*)(x + (size_t)row * K_IN);

    float4 v[4];
#pragma unroll
    for (int p = 0; p < 4; p++) v[p] = rp[p * 256 + t];

    float amax = 0.f;
#pragma unroll
    for (int p = 0; p < 4; p++)
      amax = fmaxf(amax, fmaxf(fmaxf(fabsf(v[p].x), fabsf(v[p].y)),
                               fmaxf(fabsf(v[p].z), fabsf(v[p].w))));

#pragma unroll
    for (int off = 32; off > 0; off >>= 1)
      amax = fmaxf(amax, __shfl_xor(amax, off));

    if ((t & 63) == 0) wmax[t >> 6] = amax;
    __syncthreads();
    amax = fmaxf(fmaxf(wmax[0], wmax[1]), fmaxf(wmax[2], wmax[3]));
    amax = fmaxf(amax, 1e-30f);

    const float inv = 127.f / amax;
    if (t == 0) scales[row] = amax / 127.f;

    uint32_t* op = (uint32_t*)(xq + (size_t)row * K_IN);
#pragma unroll
    for (int p = 0; p < 4; p++) {
      uint32_t b0 = (uint32_t)(__float2int_rn(v[p].x * inv) & 0xFF);
      uint32_t b1 = (uint32_t)(__float2int_rn(v[p].y * inv) & 0xFF);
      uint32_t b2 = (uint32_t)(__float2int_rn(v[p].z * inv) & 0xFF);
      uint32_t b3 = (uint32_t)(__float2int_rn(v[p].w * inv) & 0xFF);
      op[p * 256 + t] = b0 | (b1 << 8) | (b2 << 16) | (b3 << 24);
    }
  } else {
    const size_t base = (size_t)(blockIdx.x - M_TOK) * 1024;  // float4 units
    const float4* p = (const float4*)w + base;
    uint32_t* op = (uint32_t*)wq + base;
#pragma unroll
    for (int q = 0; q < 4; q++) {
      float4 f = p[q * 256 + t];
      int s0 = (f.x > 0.f) - (f.x < 0.f);
      int s1 = (f.y > 0.f) - (f.y < 0.f);
      int s2 = (f.z > 0.f) - (f.z < 0.f);
      int s3 = (f.w > 0.f) - (f.w < 0.f);
      op[q * 256 + t] = (uint32_t)(s0 & 0xFF) | ((uint32_t)(s1 & 0xFF) << 8) |
                        ((uint32_t)(s2 & 0xFF) << 16) | ((uint32_t)(s3 & 0xFF) << 24);
    }
  }
}

// ---------------------------------------------------------------------------
// C[m][n] = scale[m] * (sum_k Aq[m][k] * Wq[n][k]) + bias[n]
//
// Round-2 ring (4 slots, prefetch distance 3, counted vmcnt, 1 barrier/tile)
// + CROSS-BARRIER REGISTER PREFETCH: iteration t's MFMAs consume fragments
// read during iteration t-1 (double-buffered in registers), so after each
// barrier the MFMA pipe starts immediately while this tile's 12 ds_reads
// (for tile t+1) fill the LDS pipe concurrently. The two co-critical pipes
// (MFMA ~1170 cyc/CU/tile, LDS-read ~1150) overlap instead of serializing.
//
// Safety: vmcnt(4) at iter t ensures MY tile-(t+1) stages landed; the barrier
// extends to all waves -> post-barrier READF(t+1) is cross-wave safe.
// Frag reads of tile t-1 are forced complete by their MFMA use at iter t-1
// (compiler lgkmcnt) before the iter-t barrier -> stage(t+3) overwriting
// slot (t-1)&3 after the barrier is WAR-safe.
//
// LDS swizzle (unchanged): row r stores 16B chunk c at slot c ^ ((r>>1)&3);
// global source pre-swizzled (lane L: chunk (L&3)^((L>>3)&3)); fragment reads
// then spread every 8 rows over all 32 banks.
// ---------------------------------------------------------------------------
struct Frags {
  i32x4 a[2][4];  // [ks][m]
  i32x4 b[2][2];  // [ks][n]
};

__global__ void __launch_bounds__(512, 2) gemm_bin_i8(
    const char* __restrict__ A, const char* __restrict__ B,
    const float* __restrict__ scales, const float* __restrict__ bias,
    float* __restrict__ C) {
  __shared__ __align__(16) char lds[4 * SLOT_BYTES];  // 128 KB

  const int tid  = threadIdx.x;
  const int lane = tid & 63;
  const int wv   = tid >> 6;   // 0..7
  const int wm   = wv >> 2;    // 0..1  (M half)
  const int wn   = wv & 3;     // 0..3  (N quarter)

  // XCD-aware bijective swizzle: 512 blocks, 8 XCDs, 64 per XCD chunk.
  int bid = (int)blockIdx.x;
  bid = (bid & 7) * (512 >> 3) + (bid >> 3);
  const int m0 = (bid >> 4) * BM;  // 32 m-tiles
  const int n0 = (bid & 15) * BN;  // 16 n-tiles

  // ---- staging: wave wv owns rows [wv*32, wv*32+32); 2 GLDS16 each for A,B.
  const int srow   = lane >> 2;                       // 0..15
  const int schunk = (lane & 3) ^ ((lane >> 3) & 3);  // pre-swizzled source chunk
  const char* gAb = A + (size_t)(m0 + wv * 32 + srow) * K_IN + schunk * 16;
  const char* gBb = B + (size_t)(n0 + wv * 32 + srow) * K_IN + schunk * 16;
  // WAVE-UNIFORM LDS bases (HW adds lane*16 itself).
  char* lAb = lds + wv * 2048;
  char* lBb = lds + B_OFF + wv * 2048;

  auto stage = [&](int tt) {
    const size_t ko = (size_t)tt * BKB;
    char* la = lAb + (tt & 3) * SLOT_BYTES;
    char* lb = lBb + (tt & 3) * SLOT_BYTES;
    GLDS16(gAb + ko, la);
    GLDS16(gAb + ko + (size_t)16 * K_IN, la + 1024);
    GLDS16(gBb + ko, lb);
    GLDS16(gBb + ko + (size_t)16 * K_IN, lb + 1024);
  };

  // ---- fragment read constants
  const int fr  = lane & 31;         // row within 32-row subtile
  const int k16 = lane >> 5;         // which 16B half of the 32-i8 k-slice
  const int x3  = (lane >> 1) & 3;   // swizzle term ((row>>1)&3)
  const int aoff = wm * 8192 + fr * 64;           // wm*128 rows
  const int boff = B_OFF + wn * 4096 + fr * 64;   // wn*64 rows
  const int so0 = ((0 + k16) ^ x3) << 4;          // ks=0 chunk offset
  const int so1 = ((2 + k16) ^ x3) << 4;          // ks=1 chunk offset

  i32x16 acc[4][2];
#pragma unroll
  for (int m = 0; m < 4; m++)
#pragma unroll
    for (int n = 0; n < 2; n++)
#pragma unroll
      for (int r = 0; r < 16; r++) acc[m][n][r] = 0;

  Frags f0, f1;

#define READF(f, tt)                                                           \
  {                                                                            \
    const char* pA_ = lds + ((tt) & 3) * SLOT_BYTES + aoff;                    \
    const char* pB_ = lds + ((tt) & 3) * SLOT_BYTES + boff;                    \
    f.a[0][0] = *(const i32x4*)(pA_ + so0);                                    \
    f.a[0][1] = *(const i32x4*)(pA_ + 2048 + so0);                             \
    f.a[0][2] = *(const i32x4*)(pA_ + 4096 + so0);                             \
    f.a[0][3] = *(const i32x4*)(pA_ + 6144 + so0);                             \
    f.b[0][0] = *(const i32x4*)(pB_ + so0);                                    \
    f.b[0][1] = *(const i32x4*)(pB_ + 2048 + so0);                             \
    f.a[1][0] = *(const i32x4*)(pA_ + so1);                                    \
    f.a[1][1] = *(const i32x4*)(pA_ + 2048 + so1);                             \
    f.a[1][2] = *(const i32x4*)(pA_ + 4096 + so1);                             \
    f.a[1][3] = *(const i32x4*)(pA_ + 6144 + so1);                             \
    f.b[1][0] = *(const i32x4*)(pB_ + so1);                                    \
    f.b[1][1] = *(const i32x4*)(pB_ + 2048 + so1);                             \
  }

#define MFMAF(f)                                                               \
  {                                                                            \
    __builtin_amdgcn_s_setprio(1);                                             \
    acc[0][0] = __builtin_amdgcn_mfma_i32_32x32x32_i8(f.a[0][0], f.b[0][0], acc[0][0], 0, 0, 0); \
    acc[0][1] = __builtin_amdgcn_mfma_i32_32x32x32_i8(f.a[0][0], f.b[0][1], acc[0][1], 0, 0, 0); \
    acc[1][0] = __builtin_amdgcn_mfma_i32_32x32x32_i8(f.a[0][1], f.b[0][0], acc[1][0], 0, 0, 0); \
    acc[1][1] = __builtin_amdgcn_mfma_i32_32x32x32_i8(f.a[0][1], f.b[0][1], acc[1][1], 0, 0, 0); \
    acc[2][0] = __builtin_amdgcn_mfma_i32_32x32x32_i8(f.a[0][2], f.b[0][0], acc[2][0], 0, 0, 0); \
    acc[2][1] = __builtin_amdgcn_mfma_i32_32x32x32_i8(f.a[0][2], f.b[0][1], acc[2][1], 0, 0, 0); \
    acc[3][0] = __builtin_amdgcn_mfma_i32_32x32x32_i8(f.a[0][3], f.b[0][0], acc[3][0], 0, 0, 0); \
    acc[3][1] = __builtin_amdgcn_mfma_i32_32x32x32_i8(f.a[0][3], f.b[0][1], acc[3][1], 0, 0, 0); \
    acc[0][0] = __builtin_amdgcn_mfma_i32_32x32x32_i8(f.a[1][0], f.b[1][0], acc[0][0], 0, 0, 0); \
    acc[0][1] = __builtin_amdgcn_mfma_i32_32x32x32_i8(f.a[1][0], f.b[1][1], acc[0][1], 0, 0, 0); \
    acc[1][0] = __builtin_amdgcn_mfma_i32_32x32x32_i8(f.a[1][1], f.b[1][0], acc[1][0], 0, 0, 0); \
    acc[1][1] = __builtin_amdgcn_mfma_i32_32x32x32_i8(f.a[1][1], f.b[1][1], acc[1][1], 0, 0, 0); \
    acc[2][0] = __builtin_amdgcn_mfma_i32_32x32x32_i8(f.a[1][2], f.b[1][0], acc[2][0], 0, 0, 0); \
    acc[2][1] = __builtin_amdgcn_mfma_i32_32x32x32_i8(f.a[1][2], f.b[1][1], acc[2][1], 0, 0, 0); \
    acc[3][0] = __builtin_amdgcn_mfma_i32_32x32x32_i8(f.a[1][3], f.b[1][0], acc[3][0], 0, 0, 0); \
    acc[3][1] = __builtin_amdgcn_mfma_i32_32x32x32_i8(f.a[1][3], f.b[1][1], acc[3][1], 0, 0, 0); \
    __builtin_amdgcn_s_setprio(0);                                             \
  }

  // iter t: wait t+1 landed -> barrier -> stage t+3 + read t+1 frags (LDS
  // pipe) while MFMAs on tile t run from registers (matrix pipe).
#define ITER(t_, fc, fn, STAGE_STMT, VM_STMT)                                  \
  {                                                                            \
    VM_STMT;                                                                   \
    SB0;                                                                       \
    __builtin_amdgcn_s_barrier();                                              \
    SB0;                                                                       \
    STAGE_STMT;                                                                \
    READF(fn, (t_) + 1);                                                       \
    MFMAF(fc);                                                                 \
  }

  // ---- prologue: stage tiles 0,1,2; tile 0 readable; preload frags(0).
  stage(0); stage(1); stage(2);
  VM8;  // tile 0 done (tiles 1,2 in flight)
  SB0;
  __builtin_amdgcn_s_barrier();
  SB0;
  READF(f0, 0);

  // ---- main loop: trips I=0..29 cover t=0..59 (stages 3..62)
  for (int I = 0; I < 30; ++I) {
    const int t0 = 2 * I;
    ITER(t0,     f0, f1, stage(t0 + 3), VM4);
    ITER(t0 + 1, f1, f0, stage(t0 + 4), VM4);
  }
  // ---- tail: t=60 (stage 63), 61, 62, 63
  ITER(60, f0, f1, stage(63), VM4);
  ITER(61, f1, f0, NOPX, VM4);
  ITER(62, f0, f1, NOPX, VM0);
  MFMAF(f1);  // t=63: no barrier/read needed (lgkm use-wait covers f1)
#undef ITER
#undef MFMAF
#undef READF

  // ---- epilogue: 32x32 C/D layout col=lane&31, row=(r&3)+8*(r>>2)+4*(lane>>5)
  const int col0 = n0 + wn * 64 + (lane & 31);
  const float bv0 = bias[col0];
  const float bv1 = bias[col0 + 32];
#pragma unroll
  for (int m = 0; m < 4; m++) {
    const int rb = m0 + wm * 128 + m * 32 + ((lane >> 5) << 2);
#pragma unroll
    for (int r = 0; r < 16; r++) {
      const int row = rb + (r & 3) + ((r >> 2) << 3);
      const float sc = scales[row];
      float* cp = C + (size_t)row * N_OUT + col0;
      cp[0]  = (float)acc[m][0][r] * sc + bv0;
      cp[32] = (float)acc[m][1][r] * sc + bv1;
    }
  }
}

// emergency fallback if ws too small (correct but slow)
__global__ void fallback_gemm(const float* __restrict__ x, const float* __restrict__ w,
                              const float* __restrict__ bias, float* __restrict__ out) {
  int idx = blockIdx.x * blockDim.x + threadIdx.x;
  if (idx >= M_TOK * N_OUT) return;
  int row = idx / N_OUT, col = idx % N_OUT;
  const float* xp = x + (size_t)row * K_IN;
  const float* wp = w + (size_t)col * K_IN;
  float s = 0.f;
  for (int k = 0; k < K_IN; k++) {
    float wv = wp[k];
    float sg = wv > 0.f ? 1.f : (wv < 0.f ? -1.f : 0.f);
    s += xp[k] * sg;
  }
  out[idx] = s + bias[col];
}

extern "C" void kernel_launch(void* const* d_in, const int* in_sizes, int n_in,
                              void* d_out, int out_size, void* d_ws, size_t ws_size,
                              hipStream_t stream) {
  const float* x    = (const float*)d_in[0];
  const float* w    = (const float*)d_in[1];
  const float* bias = (const float*)d_in[2];
  float* out = (float*)d_out;

  const size_t xq_bytes = (size_t)M_TOK * K_IN;           // 32 MiB
  const size_t wq_bytes = (size_t)N_OUT * K_IN;           // 16 MiB
  const size_t sc_bytes = (size_t)M_TOK * sizeof(float);  // 32 KiB

  if (ws_size < xq_bytes + wq_bytes + sc_bytes) {
    int total = M_TOK * N_OUT;
    fallback_gemm<<<(total + 255) / 256, 256, 0, stream>>>(x, w, bias, out);
    return;
  }

  char*  xq = (char*)d_ws;
  char*  wq = (char*)d_ws + xq_bytes;
  float* sc = (float*)((char*)d_ws + xq_bytes + wq_bytes);

  // one fused quant launch: 8192 x-row blocks + 4096 w-sign blocks
  quant_fused<<<M_TOK + (N_OUT * K_IN / 4) / 1024, 256, 0, stream>>>(x, w, xq, wq, sc);

  // 32 x 16 = 512 blocks of 512 threads (8 waves), 128 KB LDS -> 1 block/CU
  gemm_bin_i8<<<512, 512, 0, stream>>>(xq, wq, sc, bias, out);
}